// Round 18
// baseline (166.833 us; speedup 1.0000x reference)
//
#include <hip/hip_runtime.h>

typedef unsigned short u16;
typedef __bf16 bf16x8 __attribute__((ext_vector_type(8)));
typedef u16 u16x8 __attribute__((ext_vector_type(8)));
typedef float f32x4 __attribute__((ext_vector_type(4)));
typedef unsigned uint2v __attribute__((ext_vector_type(2)));

#define LOG2E 1.4426950408889634f

static __device__ __forceinline__ u16 f2bf(float f) {
    union { float f; unsigned u; } x; x.f = f;
    unsigned r = x.u + 0x7fffu + ((x.u >> 16) & 1u);
    return (u16)(r >> 16);
}

static __device__ __forceinline__ unsigned cvtpk(float lo, float hi) {
    unsigned r;
    asm("v_cvt_pk_bf16_f32 %0, %1, %2" : "=v"(r) : "v"(lo), "v"(hi));
    return r;
}

static __device__ __forceinline__ void gl_lds16(const void* g, void* l) {
    __builtin_amdgcn_global_load_lds(
        (const __attribute__((address_space(1))) void*)g,
        (__attribute__((address_space(3))) void*)l, 16, 0, 0);
}

// ---------------- fp32 -> bf16 conversion (hidden states) ----------------
__global__ __launch_bounds__(256) void cvt_k(const float* __restrict__ src,
                                             u16* __restrict__ dst, int n) {
    int i = (blockIdx.x * 256 + threadIdx.x) * 4;
    if (i < n) {
        float4 v = *(const float4*)(src + i);
        ushort4 o;
        o.x = f2bf(v.x); o.y = f2bf(v.y); o.z = f2bf(v.z); o.w = f2bf(v.w);
        *(ushort4*)(dst + i) = o;
    }
}

// ---------------- weight transpose + cvt: W[K][N] fp32 -> WT[N][K] bf16 ----
__global__ __launch_bounds__(256) void transw_k(const float* __restrict__ w0,
                                                const float* __restrict__ w1,
                                                const float* __restrict__ w2,
                                                const float* __restrict__ w3,
                                                u16* __restrict__ wt) {
    __shared__ float T[64][65];
    const float* src = (blockIdx.z == 0) ? w0 : (blockIdx.z == 1) ? w1
                     : (blockIdx.z == 2) ? w2 : w3;
    u16* dst = wt + (size_t)blockIdx.z * 1048576;
    const int k0 = blockIdx.x * 64, n0 = blockIdx.y * 64;
    const int rr = threadIdx.x >> 6, col = threadIdx.x & 63;
#pragma unroll
    for (int i = 0; i < 16; ++i) {
        int row = i * 4 + rr;
        T[row][col] = src[(size_t)(k0 + row) * 1024 + n0 + col];
    }
    __syncthreads();
#pragma unroll
    for (int i = 0; i < 16; ++i) {
        int row = i * 4 + rr;
        dst[(size_t)(n0 + row) * 1024 + k0 + col] = f2bf(T[col][row]);
    }
}

// ---------------- bf16 GEMM, split per mode (R16 structure) ---------------
// MODE 0: QK fused (grid.y=16, sel=y>>3). MODE 2: V^T (grid.y=8, swapped
// MFMA). MODE 1: O-proj (grid.y=8, fp32 out). BK=64, T2 XOR swizzle,
// single compiled K-loop body per kernel.
template<int MODE>
__global__ __launch_bounds__(256) void gemm_t(
    const u16* __restrict__ A, const u16* __restrict__ WT0,
    const float* __restrict__ b0, const float* __restrict__ b1,
    u16* __restrict__ o0, u16* __restrict__ o1, float* __restrict__ oF) {
    __shared__ alignas(16) u16 Al[128 * 64];
    __shared__ alignas(16) u16 Bl[128 * 64];

    const int tid = threadIdx.x;
    const int lane = tid & 63;
    const int wv = tid >> 6;
    const int wr = wv >> 1, wc = wv & 1;
    const int l15 = lane & 15, l4 = lane >> 4;

    const int mbase = blockIdx.x * 128;
    const int sel = (MODE == 0) ? (blockIdx.y >> 3) : 0;
    const int nb = (blockIdx.y & 7) * 128;

    const u16* Ab = A + (size_t)mbase * 1024;
    const u16* Bb = WT0 + (size_t)sel * 1048576 + (size_t)nb * 1024;

    const int lr8 = lane >> 3;
    const int ls = lane & 7;

    f32x4 acc[4][4] = {};

    auto stage = [&](const u16* src, u16* dstL, int k0) {
#pragma unroll
        for (int i = 0; i < 4; ++i) {
            int r = i * 32 + wv * 8 + lr8;
            gl_lds16(src + (size_t)r * 1024 + k0 + ((ls ^ (r & 7)) * 8),
                     dstL + (i * 2048 + wv * 512));
        }
    };

    for (int k0 = 0; k0 < 1024; k0 += 64) {
        stage(Ab, Al, k0);
        stage(Bb, Bl, k0);
        __syncthreads();
#pragma unroll
        for (int ks = 0; ks < 2; ++ks) {
            bf16x8 af[4], bfr[4];
#pragma unroll
            for (int mr = 0; mr < 4; ++mr) {
                int r = wr * 64 + mr * 16 + l15;
                af[mr] = *(const bf16x8*)(Al + r * 64 + (((ks * 4 + l4) ^ (r & 7)) * 8));
            }
#pragma unroll
            for (int nr = 0; nr < 4; ++nr) {
                int r = wc * 64 + nr * 16 + l15;
                bfr[nr] = *(const bf16x8*)(Bl + r * 64 + (((ks * 4 + l4) ^ (r & 7)) * 8));
            }
            if constexpr (MODE == 2) {
#pragma unroll
                for (int mr = 0; mr < 4; ++mr)
#pragma unroll
                    for (int nr = 0; nr < 4; ++nr)
                        acc[mr][nr] = __builtin_amdgcn_mfma_f32_16x16x32_bf16(
                            bfr[nr], af[mr], acc[mr][nr], 0, 0, 0);
            } else {
#pragma unroll
                for (int mr = 0; mr < 4; ++mr)
#pragma unroll
                    for (int nr = 0; nr < 4; ++nr)
                        acc[mr][nr] = __builtin_amdgcn_mfma_f32_16x16x32_bf16(
                            af[mr], bfr[nr], acc[mr][nr], 0, 0, 0);
            }
        }
        __syncthreads();
    }

    if constexpr (MODE == 2) {
        // V^T epilogue: lane holds row d, col s
#pragma unroll
        for (int mr = 0; mr < 4; ++mr) {
            int srow2 = mbase + wr * 64 + mr * 16 + l15;
            int b_ = srow2 >> 12, s_ = srow2 & 4095;
#pragma unroll
            for (int nr = 0; nr < 4; ++nr) {
                f32x4 bvv = *(const f32x4*)(b0 + nb + wc * 64 + nr * 16 + l4 * 4);
#pragma unroll
                for (int j = 0; j < 4; ++j) {
                    int c2 = nb + wc * 64 + nr * 16 + l4 * 4 + j;  // h*64+d
                    float v = acc[mr][nr][j] + bvv[j];
                    o0[(((size_t)(b_ * 16 + (c2 >> 6)) * 64 + (c2 & 63)) * 4096) + s_] = f2bf(v);
                }
            }
        }
        return;
    }

    const float* bias = (MODE == 0 && sel == 1) ? b1 : b0;
    u16* oH = (sel == 0) ? o0 : o1;
    const float scale = (MODE == 0 && sel == 0) ? 0.125f * LOG2E : 1.0f;

#pragma unroll
    for (int mr = 0; mr < 4; ++mr)
#pragma unroll
        for (int nr = 0; nr < 4; ++nr) {
            int col = nb + wc * 64 + nr * 16 + l15;
            float bv_ = bias[col];
#pragma unroll
            for (int j = 0; j < 4; ++j) {
                int row = mbase + wr * 64 + mr * 16 + l4 * 4 + j;
                float v = (acc[mr][nr][j] + bv_) * scale;
                if constexpr (MODE == 0) {
                    int b_ = row >> 12, s_ = row & 4095;
                    int h_ = col >> 6, d_ = col & 63;
                    oH[(((size_t)(b_ * 16 + h_) * 4096) + s_) * 64 + d_] = f2bf(v);
                } else {
                    oF[(size_t)row * 1024 + col] = v;
                }
            }
        }
}

// ---------------- sliding-window attention (R17 verbatim) -----------------
// Mask-zero fast path + double P buffer + K/V^T DMA staging + defer-max.
__global__ __launch_bounds__(256) void attn_k(
    const u16* __restrict__ Qh, const u16* __restrict__ Kh,
    const u16* __restrict__ Vt, const float* __restrict__ mask,
    u16* __restrict__ attnb) {
    __shared__ alignas(16) u16 Kt[2][4096];     // [key][64 d], slot XOR swizzle
    __shared__ alignas(16) u16 VtL[2][4096];    // [d][64 key], slot XOR swizzle
    __shared__ alignas(16) u16 Pl[4][2][1024];  // per wave, per qt: [16 q][64 k]
    __shared__ alignas(16) float maskl[640];
    __shared__ int anymask;

    const int tid = threadIdx.x;
    const int lane = tid & 63;
    const int wv = tid >> 6;
    const int hw = blockIdx.x;
    const int lg = (hw & 7) * 128 + (hw >> 3);   // bijective XCD chunk swizzle
    const int c = lg & 31;
    const int h = (lg >> 5) & 15;
    const int b = lg >> 9;

    const size_t bh = (size_t)(b * 16 + h) * 4096;
    const u16* Qb = Qh + bh * 64;
    const u16* Kb = Kh + bh * 64;
    const u16* Vb = Vt + bh * 64;                // V^T rows d, stride 4096
    const float* mb = mask + b * 4096;

    const int l15 = lane & 15;
    const int l4 = lane >> 4;
    const int qbase = c * 128 + wv * 32;
    const int gkbase = c * 128 - 256;

    bf16x8 qf[2][2];
#pragma unroll
    for (int qt = 0; qt < 2; ++qt)
#pragma unroll
        for (int kc = 0; kc < 2; ++kc)
            qf[qt][kc] = *(const bf16x8*)(Qb + (size_t)(qbase + qt * 16 + l15) * 64 + kc * 32 + l4 * 8);

    f32x4 Ov[4][2] = {};
    float lsum[2] = {0.f, 0.f};
    float m[2] = {-3.0e38f, -3.0e38f};

    auto stageK = [&](int buf, int gk) {
#pragma unroll
        for (int i = 0; i < 2; ++i) {
            int r = i * 32 + wv * 8 + (lane >> 3);
            int s = lane & 7;
            int key = min(max(gk + r, 0), 4095);
            gl_lds16(Kb + (size_t)key * 64 + ((s ^ (r & 7)) * 8),
                     &Kt[buf][(i * 32 + wv * 8) * 64]);
        }
    };
    auto stageV = [&](int buf, int gk) {
#pragma unroll
        for (int i = 0; i < 2; ++i) {
            int d = i * 32 + wv * 8 + (lane >> 3);
            int s = lane & 7;
            int col = min(max(gk + ((s ^ (d & 7)) * 8), 0), 4088);
            gl_lds16(Vb + (size_t)d * 4096 + col, &VtL[buf][(i * 32 + wv * 8) * 64]);
        }
    };

    if (tid == 0) anymask = 0;
    __syncthreads();

    stageK(0, gkbase);
    stageV(0, gkbase);
    {
        int f = 0;
        for (int i = tid; i < 640; i += 256) {
            int gm = gkbase + i;
            float v = (gm >= 0 && gm < 4096) ? mb[gm] : 0.f;
            f |= (v != 0.f);
            maskl[i] = v * LOG2E;
        }
        if (f) anymask = 1;
    }
    __syncthreads();
    const bool useMask = (anymask != 0);

    const int tmin = wv >> 1;
    const int tmaxw = 8 + (wv >> 1);

    for (int t = 0; t < 10; ++t) {
        const int cur = t & 1, nxt = cur ^ 1;
        const int gk0 = gkbase + t * 64;
        if (t < 9) { stageK(nxt, gk0 + 64); stageV(nxt, gk0 + 64); }

        if (t >= tmin && t <= tmaxw) {
            f32x4 sc[4][2] = {};
            __builtin_amdgcn_s_setprio(1);
#pragma unroll
            for (int kc = 0; kc < 2; ++kc)
#pragma unroll
                for (int kb = 0; kb < 4; ++kb) {
                    int r = kb * 16 + l15;
                    bf16x8 kf = *(const bf16x8*)(&Kt[cur][r * 64 + (((kc * 4 + l4) ^ (r & 7)) * 8)]);
                    sc[kb][0] = __builtin_amdgcn_mfma_f32_16x16x32_bf16(kf, qf[0][kc], sc[kb][0], 0, 0, 0);
                    sc[kb][1] = __builtin_amdgcn_mfma_f32_16x16x32_bf16(kf, qf[1][kc], sc[kb][1], 0, 0, 0);
                }
            __builtin_amdgcn_s_setprio(0);

            const int dkq = gk0 - qbase;
            const bool full = (dkq >= -225) && (dkq <= 193) && (gk0 >= 0) && (gk0 <= 4032);
            if (full) {
                if (useMask) {
                    f32x4 mv[4];
#pragma unroll
                    for (int kb = 0; kb < 4; ++kb)
                        mv[kb] = *(const f32x4*)(maskl + t * 64 + kb * 16 + l4 * 4);
#pragma unroll
                    for (int kb = 0; kb < 4; ++kb)
#pragma unroll
                        for (int qt = 0; qt < 2; ++qt)
#pragma unroll
                            for (int j = 0; j < 4; ++j)
                                sc[kb][qt][j] += mv[kb][j];
                }
            } else {
                f32x4 mv[4];
                if (useMask) {
#pragma unroll
                    for (int kb = 0; kb < 4; ++kb)
                        mv[kb] = *(const f32x4*)(maskl + t * 64 + kb * 16 + l4 * 4);
                } else {
#pragma unroll
                    for (int kb = 0; kb < 4; ++kb) mv[kb] = f32x4{0.f, 0.f, 0.f, 0.f};
                }
                const int kb0 = gk0 + l4 * 4;
                const int ub0 = kb0 - (qbase + l15) + 256;
#pragma unroll
                for (int kb = 0; kb < 4; ++kb)
#pragma unroll
                    for (int qt = 0; qt < 2; ++qt)
#pragma unroll
                        for (int j = 0; j < 4; ++j) {
                            float sv = sc[kb][qt][j] + mv[kb][j];
                            unsigned band = (unsigned)(ub0 + kb * 16 + j - qt * 16);
                            unsigned keyv = (unsigned)(kb0 + kb * 16 + j);
                            bool ok = (band <= 512u) && (keyv < 4096u);
                            sc[kb][qt][j] = ok ? sv : -3.0e9f;
                        }
            }

            // softmax + P-write for BOTH q-halves (independent buffers)
#pragma unroll
            for (int qt = 0; qt < 2; ++qt) {
                u16* Pw = &Pl[wv][qt][0];
                const int prow = l15 * 64;
                float mx = sc[0][qt][0];
#pragma unroll
                for (int kb = 0; kb < 4; ++kb)
#pragma unroll
                    for (int j = 0; j < 4; ++j) mx = fmaxf(mx, sc[kb][qt][j]);
                if (!__all(mx <= m[qt] + 8.0f)) {
                    mx = fmaxf(mx, __shfl_xor(mx, 16));
                    mx = fmaxf(mx, __shfl_xor(mx, 32));
                    float mnew = fmaxf(m[qt], mx);
                    float alpha = exp2f(m[qt] - mnew);
                    m[qt] = mnew;
                    lsum[qt] *= alpha;
#pragma unroll
                    for (int nd = 0; nd < 4; ++nd) Ov[nd][qt] *= alpha;
                }

                float s0 = 0.f;
#pragma unroll
                for (int kb = 0; kb < 4; ++kb) {
                    float p0 = exp2f(sc[kb][qt][0] - m[qt]);
                    float p1 = exp2f(sc[kb][qt][1] - m[qt]);
                    float p2 = exp2f(sc[kb][qt][2] - m[qt]);
                    float p3 = exp2f(sc[kb][qt][3] - m[qt]);
                    s0 += (p0 + p1) + (p2 + p3);
                    uint2v pk;
                    pk[0] = cvtpk(p0, p1);
                    pk[1] = cvtpk(p2, p3);
                    int g = (((kb * 2 + (l4 >> 1)) ^ (l15 & 7)) * 8) + (l4 & 1) * 4;
                    *(uint2v*)(Pw + prow + g) = pk;
                }
                lsum[qt] += s0;
            }

            // PV: kc-outer, V fragments hoisted + shared across both q-halves
#pragma unroll
            for (int kc = 0; kc < 2; ++kc) {
                bf16x8 vf[4];
#pragma unroll
                for (int nd = 0; nd < 4; ++nd) {
                    int r2 = nd * 16 + l15;
                    vf[nd] = *(const bf16x8*)(&VtL[cur][r2 * 64 +
                        (((kc * 4 + l4) ^ (r2 & 7)) * 8)]);
                }
#pragma unroll
                for (int qt = 0; qt < 2; ++qt) {
                    bf16x8 pf = *(const bf16x8*)(&Pl[wv][qt][0] + l15 * 64 +
                                                 (((kc * 4 + l4) ^ (l15 & 7)) * 8));
                    __builtin_amdgcn_s_setprio(1);
#pragma unroll
                    for (int nd = 0; nd < 4; ++nd)
                        Ov[nd][qt] = __builtin_amdgcn_mfma_f32_16x16x32_bf16(vf[nd], pf, Ov[nd][qt], 0, 0, 0);
                    __builtin_amdgcn_s_setprio(0);
                }
            }
        }
        __syncthreads();
    }

    lsum[0] += __shfl_xor(lsum[0], 16);
    lsum[0] += __shfl_xor(lsum[0], 32);
    lsum[1] += __shfl_xor(lsum[1], 16);
    lsum[1] += __shfl_xor(lsum[1], 32);
    float inv0 = 1.0f / lsum[0];
    float inv1 = 1.0f / lsum[1];
#pragma unroll
    for (int qt = 0; qt < 2; ++qt) {
        float inv = qt ? inv1 : inv0;
        size_t rowb = ((size_t)b * 4096 + qbase + qt * 16 + l15) * 1024 + h * 64 + l4 * 4;
#pragma unroll
        for (int nd = 0; nd < 4; ++nd) {
            uint2v o;
            o[0] = cvtpk(Ov[nd][qt][0] * inv, Ov[nd][qt][1] * inv);
            o[1] = cvtpk(Ov[nd][qt][2] * inv, Ov[nd][qt][3] * inv);
            *(uint2v*)(&attnb[rowb + nd * 16]) = o;
        }
    }
}

// ---------------------------------------------------------------------------
extern "C" void kernel_launch(void* const* d_in, const int* in_sizes, int n_in,
                              void* d_out, int out_size, void* d_ws, size_t ws_size,
                              hipStream_t stream) {
    (void)in_sizes; (void)n_in; (void)out_size; (void)ws_size;
    const float* hid  = (const float*)d_in[0];
    const float* mask = (const float*)d_in[1];
    const float* Wq = (const float*)d_in[2];
    const float* bq = (const float*)d_in[3];
    const float* Wk = (const float*)d_in[4];
    const float* bk = (const float*)d_in[5];
    const float* Wv = (const float*)d_in[6];
    const float* bv = (const float*)d_in[7];
    const float* Wo = (const float*)d_in[8];
    const float* bo = (const float*)d_in[9];
    float* out = (float*)d_out;

    char* ws = (char*)d_ws;
    u16* hidb  = (u16*)(ws);
    u16* wt    = (u16*)(ws + (16u << 20));
    u16* Qh    = (u16*)(ws + (24u << 20));
    u16* Kh    = (u16*)(ws + (40u << 20));
    u16* Vtb   = (u16*)(ws + (56u << 20));   // V^T [B][H][64][4096]
    u16* attnb = (u16*)(ws + (72u << 20));

    cvt_k<<<dim3(8192), dim3(256), 0, stream>>>(hid, hidb, 8388608);
    transw_k<<<dim3(16, 16, 4), dim3(256), 0, stream>>>(Wq, Wk, Wv, Wo, wt);
    gemm_t<0><<<dim3(64, 16), dim3(256), 0, stream>>>(hidb, wt, bq, bk,
                                                      Qh, Kh, (float*)nullptr);
    gemm_t<2><<<dim3(64, 8), dim3(256), 0, stream>>>(hidb, wt + 2 * 1048576, bv, (const float*)nullptr,
                                                     Vtb, (u16*)nullptr, (float*)nullptr);
    attn_k<<<dim3(1024), dim3(256), 0, stream>>>(Qh, Kh, Vtb, mask, attnb);
    gemm_t<1><<<dim3(64, 8), dim3(256), 0, stream>>>(attnb, wt + 3 * 1048576, bo, (const float*)nullptr,
                                                     (u16*)nullptr, (u16*)nullptr, out);
}

// Round 19
// 163.892 us; speedup vs baseline: 1.0179x; 1.0179x over previous
//
#include <hip/hip_runtime.h>

typedef unsigned short u16;
typedef __bf16 bf16x8 __attribute__((ext_vector_type(8)));
typedef u16 u16x8 __attribute__((ext_vector_type(8)));
typedef float f32x4 __attribute__((ext_vector_type(4)));
typedef unsigned uint2v __attribute__((ext_vector_type(2)));

#define LOG2E 1.4426950408889634f

static __device__ __forceinline__ u16 f2bf(float f) {
    union { float f; unsigned u; } x; x.f = f;
    unsigned r = x.u + 0x7fffu + ((x.u >> 16) & 1u);
    return (u16)(r >> 16);
}

static __device__ __forceinline__ unsigned cvtpk(float lo, float hi) {
    unsigned r;
    asm("v_cvt_pk_bf16_f32 %0, %1, %2" : "=v"(r) : "v"(lo), "v"(hi));
    return r;
}

static __device__ __forceinline__ void gl_lds16(const void* g, void* l) {
    __builtin_amdgcn_global_load_lds(
        (const __attribute__((address_space(1))) void*)g,
        (__attribute__((address_space(3))) void*)l, 16, 0, 0);
}

// ---------------- fp32 -> bf16 conversion (hidden states) ----------------
__global__ __launch_bounds__(256) void cvt_k(const float* __restrict__ src,
                                             u16* __restrict__ dst, int n) {
    int i = (blockIdx.x * 256 + threadIdx.x) * 4;
    if (i < n) {
        float4 v = *(const float4*)(src + i);
        ushort4 o;
        o.x = f2bf(v.x); o.y = f2bf(v.y); o.z = f2bf(v.z); o.w = f2bf(v.w);
        *(ushort4*)(dst + i) = o;
    }
}

// ---------------- weight transpose + cvt: W[K][N] fp32 -> WT[N][K] bf16 ----
__global__ __launch_bounds__(256) void transw_k(const float* __restrict__ w0,
                                                const float* __restrict__ w1,
                                                const float* __restrict__ w2,
                                                const float* __restrict__ w3,
                                                u16* __restrict__ wt) {
    __shared__ float T[64][65];
    const float* src = (blockIdx.z == 0) ? w0 : (blockIdx.z == 1) ? w1
                     : (blockIdx.z == 2) ? w2 : w3;
    u16* dst = wt + (size_t)blockIdx.z * 1048576;
    const int k0 = blockIdx.x * 64, n0 = blockIdx.y * 64;
    const int rr = threadIdx.x >> 6, col = threadIdx.x & 63;
#pragma unroll
    for (int i = 0; i < 16; ++i) {
        int row = i * 4 + rr;
        T[row][col] = src[(size_t)(k0 + row) * 1024 + n0 + col];
    }
    __syncthreads();
#pragma unroll
    for (int i = 0; i < 16; ++i) {
        int row = i * 4 + rr;
        dst[(size_t)(n0 + row) * 1024 + k0 + col] = f2bf(T[col][row]);
    }
}

// ---------------- bf16 GEMM, compile-time specialized (R16 verbatim) ------
// MODE 0: QK fused (grid.y=16, sel=y>>3): head-major bf16 out, Q scaled.
// MODE 2: V^T (grid.y=8): swapped-operand MFMA, out [B,H,64,S] bf16.
// MODE 1: O-proj (grid.y=8): fp32 row-major out.
// BK=64, T2 XOR swizzle (0 bank conflicts, measured R17).
template<int MODE>
__global__ __launch_bounds__(256) void gemm_t(
    const u16* __restrict__ A, const u16* __restrict__ WT0,
    const float* __restrict__ b0, const float* __restrict__ b1,
    u16* __restrict__ o0, u16* __restrict__ o1, float* __restrict__ oF) {
    __shared__ alignas(16) u16 Al[128 * 64];
    __shared__ alignas(16) u16 Bl[128 * 64];

    const int tid = threadIdx.x;
    const int lane = tid & 63;
    const int wv = tid >> 6;
    const int wr = wv >> 1, wc = wv & 1;
    const int l15 = lane & 15, l4 = lane >> 4;

    const int mbase = blockIdx.x * 128;
    const int sel = (MODE == 0) ? (blockIdx.y >> 3) : 0;
    const int nb = (blockIdx.y & 7) * 128;

    const u16* Ab = A + (size_t)mbase * 1024;
    const u16* Bb = WT0 + (size_t)sel * 1048576 + (size_t)nb * 1024;

    const int lr8 = lane >> 3;           // row-in-8-group
    const int ls = lane & 7;             // 16B slot

    f32x4 acc[4][4] = {};

    // stage one 128x64 tile: linear LDS dest, source col pre-swizzled so
    // LDS[r][s] = global[r][s ^ (r&7)]
    auto stage = [&](const u16* src, u16* dstL, int k0) {
#pragma unroll
        for (int i = 0; i < 4; ++i) {
            int r = i * 32 + wv * 8 + lr8;
            gl_lds16(src + (size_t)r * 1024 + k0 + ((ls ^ (r & 7)) * 8),
                     dstL + (i * 2048 + wv * 512));
        }
    };

    for (int k0 = 0; k0 < 1024; k0 += 64) {
        stage(Ab, Al, k0);
        stage(Bb, Bl, k0);
        __syncthreads();

#pragma unroll
        for (int ks = 0; ks < 2; ++ks) {
            bf16x8 af[4], bfr[4];
#pragma unroll
            for (int mr = 0; mr < 4; ++mr) {
                int r = wr * 64 + mr * 16 + l15;
                af[mr] = *(const bf16x8*)(Al + r * 64 + (((ks * 4 + l4) ^ (r & 7)) * 8));
            }
#pragma unroll
            for (int nr = 0; nr < 4; ++nr) {
                int r = wc * 64 + nr * 16 + l15;
                bfr[nr] = *(const bf16x8*)(Bl + r * 64 + (((ks * 4 + l4) ^ (r & 7)) * 8));
            }
            if constexpr (MODE == 2) {
#pragma unroll
                for (int mr = 0; mr < 4; ++mr)
#pragma unroll
                    for (int nr = 0; nr < 4; ++nr)
                        acc[mr][nr] = __builtin_amdgcn_mfma_f32_16x16x32_bf16(
                            bfr[nr], af[mr], acc[mr][nr], 0, 0, 0);
            } else {
#pragma unroll
                for (int mr = 0; mr < 4; ++mr)
#pragma unroll
                    for (int nr = 0; nr < 4; ++nr)
                        acc[mr][nr] = __builtin_amdgcn_mfma_f32_16x16x32_bf16(
                            af[mr], bfr[nr], acc[mr][nr], 0, 0, 0);
            }
        }
        __syncthreads();
    }

    if constexpr (MODE == 2) {
        // V^T epilogue (R11/R12-proven): lane holds row d, col s
#pragma unroll
        for (int mr = 0; mr < 4; ++mr) {
            int srow2 = mbase + wr * 64 + mr * 16 + l15;
            int b_ = srow2 >> 12, s_ = srow2 & 4095;
#pragma unroll
            for (int nr = 0; nr < 4; ++nr) {
                f32x4 bvv = *(const f32x4*)(b0 + nb + wc * 64 + nr * 16 + l4 * 4);
#pragma unroll
                for (int j = 0; j < 4; ++j) {
                    int c2 = nb + wc * 64 + nr * 16 + l4 * 4 + j;  // h*64+d
                    float v = acc[mr][nr][j] + bvv[j];
                    o0[(((size_t)(b_ * 16 + (c2 >> 6)) * 64 + (c2 & 63)) * 4096) + s_] = f2bf(v);
                }
            }
        }
        return;
    }

    const float* bias = (MODE == 0 && sel == 1) ? b1 : b0;
    u16* oH = (sel == 0) ? o0 : o1;
    const float scale = (MODE == 0 && sel == 0) ? 0.125f * LOG2E : 1.0f;

#pragma unroll
    for (int mr = 0; mr < 4; ++mr)
#pragma unroll
        for (int nr = 0; nr < 4; ++nr) {
            int col = nb + wc * 64 + nr * 16 + l15;
            float bv_ = bias[col];
#pragma unroll
            for (int j = 0; j < 4; ++j) {
                int row = mbase + wr * 64 + mr * 16 + l4 * 4 + j;
                float v = (acc[mr][nr][j] + bv_) * scale;
                if constexpr (MODE == 0) {
                    int b_ = row >> 12, s_ = row & 4095;
                    int h_ = col >> 6, d_ = col & 63;
                    oH[(((size_t)(b_ * 16 + h_) * 4096) + s_) * 64 + d_] = f2bf(v);
                } else {
                    oF[(size_t)row * 1024 + col] = v;
                }
            }
        }
}

// ---------------- sliding-window attention (R15/R16 verbatim) -------------
// Double P buffer + K/V^T DMA staging (slot XOR swizzle) + per-q defer-max
// softmax + full-tile fast path + kc-outer PV with hoisted V fragments.
// NO mask-zero branch (measured +4us regression in R18).
__global__ __launch_bounds__(256) void attn_k(
    const u16* __restrict__ Qh, const u16* __restrict__ Kh,
    const u16* __restrict__ Vt, const float* __restrict__ mask,
    u16* __restrict__ attnb) {
    __shared__ alignas(16) u16 Kt[2][4096];     // [key][64 d], slot XOR swizzle
    __shared__ alignas(16) u16 VtL[2][4096];    // [d][64 key], slot XOR swizzle
    __shared__ alignas(16) u16 Pl[4][2][1024];  // per wave, per qt: [16 q][64 k]
    __shared__ alignas(16) float maskl[640];

    const int tid = threadIdx.x;
    const int lane = tid & 63;
    const int wv = tid >> 6;
    const int hw = blockIdx.x;
    const int lg = (hw & 7) * 128 + (hw >> 3);   // bijective XCD chunk swizzle
    const int c = lg & 31;
    const int h = (lg >> 5) & 15;
    const int b = lg >> 9;

    const size_t bh = (size_t)(b * 16 + h) * 4096;
    const u16* Qb = Qh + bh * 64;
    const u16* Kb = Kh + bh * 64;
    const u16* Vb = Vt + bh * 64;                // V^T rows d, stride 4096
    const float* mb = mask + b * 4096;

    const int l15 = lane & 15;
    const int l4 = lane >> 4;
    const int qbase = c * 128 + wv * 32;
    const int gkbase = c * 128 - 256;

    bf16x8 qf[2][2];
#pragma unroll
    for (int qt = 0; qt < 2; ++qt)
#pragma unroll
        for (int kc = 0; kc < 2; ++kc)
            qf[qt][kc] = *(const bf16x8*)(Qb + (size_t)(qbase + qt * 16 + l15) * 64 + kc * 32 + l4 * 8);

    f32x4 Ov[4][2] = {};
    float lsum[2] = {0.f, 0.f};
    float m[2] = {-3.0e38f, -3.0e38f};

    auto stageK = [&](int buf, int gk) {
#pragma unroll
        for (int i = 0; i < 2; ++i) {
            int r = i * 32 + wv * 8 + (lane >> 3);
            int s = lane & 7;
            int key = min(max(gk + r, 0), 4095);
            gl_lds16(Kb + (size_t)key * 64 + ((s ^ (r & 7)) * 8),
                     &Kt[buf][(i * 32 + wv * 8) * 64]);
        }
    };
    auto stageV = [&](int buf, int gk) {
#pragma unroll
        for (int i = 0; i < 2; ++i) {
            int d = i * 32 + wv * 8 + (lane >> 3);
            int s = lane & 7;
            int col = min(max(gk + ((s ^ (d & 7)) * 8), 0), 4088);
            gl_lds16(Vb + (size_t)d * 4096 + col, &VtL[buf][(i * 32 + wv * 8) * 64]);
        }
    };

    stageK(0, gkbase);
    stageV(0, gkbase);
    for (int i = tid; i < 640; i += 256) {
        int gm = gkbase + i;
        maskl[i] = (gm >= 0 && gm < 4096) ? mb[gm] * LOG2E : 0.f;
    }
    __syncthreads();

    const int tmin = wv >> 1;
    const int tmaxw = 8 + (wv >> 1);

    for (int t = 0; t < 10; ++t) {
        const int cur = t & 1, nxt = cur ^ 1;
        const int gk0 = gkbase + t * 64;
        if (t < 9) { stageK(nxt, gk0 + 64); stageV(nxt, gk0 + 64); }

        if (t >= tmin && t <= tmaxw) {
            f32x4 mv[4];
#pragma unroll
            for (int kb = 0; kb < 4; ++kb)
                mv[kb] = *(const f32x4*)(maskl + t * 64 + kb * 16 + l4 * 4);

            f32x4 sc[4][2] = {};
            __builtin_amdgcn_s_setprio(1);
#pragma unroll
            for (int kc = 0; kc < 2; ++kc)
#pragma unroll
                for (int kb = 0; kb < 4; ++kb) {
                    int r = kb * 16 + l15;
                    bf16x8 kf = *(const bf16x8*)(&Kt[cur][r * 64 + (((kc * 4 + l4) ^ (r & 7)) * 8)]);
                    sc[kb][0] = __builtin_amdgcn_mfma_f32_16x16x32_bf16(kf, qf[0][kc], sc[kb][0], 0, 0, 0);
                    sc[kb][1] = __builtin_amdgcn_mfma_f32_16x16x32_bf16(kf, qf[1][kc], sc[kb][1], 0, 0, 0);
                }
            __builtin_amdgcn_s_setprio(0);

            const int dkq = gk0 - qbase;
            const bool full = (dkq >= -225) && (dkq <= 193) && (gk0 >= 0) && (gk0 <= 4032);
            if (full) {
#pragma unroll
                for (int kb = 0; kb < 4; ++kb)
#pragma unroll
                    for (int qt = 0; qt < 2; ++qt)
#pragma unroll
                        for (int j = 0; j < 4; ++j)
                            sc[kb][qt][j] += mv[kb][j];
            } else {
                const int kb0 = gk0 + l4 * 4;
                const int ub0 = kb0 - (qbase + l15) + 256;
#pragma unroll
                for (int kb = 0; kb < 4; ++kb)
#pragma unroll
                    for (int qt = 0; qt < 2; ++qt)
#pragma unroll
                        for (int j = 0; j < 4; ++j) {
                            float sv = sc[kb][qt][j] + mv[kb][j];
                            unsigned band = (unsigned)(ub0 + kb * 16 + j - qt * 16);
                            unsigned keyv = (unsigned)(kb0 + kb * 16 + j);
                            bool ok = (band <= 512u) && (keyv < 4096u);
                            sc[kb][qt][j] = ok ? sv : -3.0e9f;
                        }
            }

            // softmax + P-write for BOTH q-halves (independent buffers)
#pragma unroll
            for (int qt = 0; qt < 2; ++qt) {
                u16* Pw = &Pl[wv][qt][0];
                const int prow = l15 * 64;
                float mx = sc[0][qt][0];
#pragma unroll
                for (int kb = 0; kb < 4; ++kb)
#pragma unroll
                    for (int j = 0; j < 4; ++j) mx = fmaxf(mx, sc[kb][qt][j]);
                if (!__all(mx <= m[qt] + 8.0f)) {
                    mx = fmaxf(mx, __shfl_xor(mx, 16));
                    mx = fmaxf(mx, __shfl_xor(mx, 32));
                    float mnew = fmaxf(m[qt], mx);
                    float alpha = exp2f(m[qt] - mnew);
                    m[qt] = mnew;
                    lsum[qt] *= alpha;
#pragma unroll
                    for (int nd = 0; nd < 4; ++nd) Ov[nd][qt] *= alpha;
                }

                float s0 = 0.f;
#pragma unroll
                for (int kb = 0; kb < 4; ++kb) {
                    float p0 = exp2f(sc[kb][qt][0] - m[qt]);
                    float p1 = exp2f(sc[kb][qt][1] - m[qt]);
                    float p2 = exp2f(sc[kb][qt][2] - m[qt]);
                    float p3 = exp2f(sc[kb][qt][3] - m[qt]);
                    s0 += (p0 + p1) + (p2 + p3);
                    uint2v pk;
                    pk[0] = cvtpk(p0, p1);
                    pk[1] = cvtpk(p2, p3);
                    int g = (((kb * 2 + (l4 >> 1)) ^ (l15 & 7)) * 8) + (l4 & 1) * 4;
                    *(uint2v*)(Pw + prow + g) = pk;
                }
                lsum[qt] += s0;
            }

            // PV: kc-outer, V fragments hoisted + shared across both q-halves
#pragma unroll
            for (int kc = 0; kc < 2; ++kc) {
                bf16x8 vf[4];
#pragma unroll
                for (int nd = 0; nd < 4; ++nd) {
                    int r2 = nd * 16 + l15;
                    vf[nd] = *(const bf16x8*)(&VtL[cur][r2 * 64 +
                        (((kc * 4 + l4) ^ (r2 & 7)) * 8)]);
                }
#pragma unroll
                for (int qt = 0; qt < 2; ++qt) {
                    bf16x8 pf = *(const bf16x8*)(&Pl[wv][qt][0] + l15 * 64 +
                                                 (((kc * 4 + l4) ^ (l15 & 7)) * 8));
                    __builtin_amdgcn_s_setprio(1);
#pragma unroll
                    for (int nd = 0; nd < 4; ++nd)
                        Ov[nd][qt] = __builtin_amdgcn_mfma_f32_16x16x32_bf16(vf[nd], pf, Ov[nd][qt], 0, 0, 0);
                    __builtin_amdgcn_s_setprio(0);
                }
            }
        }
        __syncthreads();
    }

    lsum[0] += __shfl_xor(lsum[0], 16);
    lsum[0] += __shfl_xor(lsum[0], 32);
    lsum[1] += __shfl_xor(lsum[1], 16);
    lsum[1] += __shfl_xor(lsum[1], 32);
    float inv0 = 1.0f / lsum[0];
    float inv1 = 1.0f / lsum[1];
#pragma unroll
    for (int qt = 0; qt < 2; ++qt) {
        float inv = qt ? inv1 : inv0;
        size_t rowb = ((size_t)b * 4096 + qbase + qt * 16 + l15) * 1024 + h * 64 + l4 * 4;
#pragma unroll
        for (int nd = 0; nd < 4; ++nd) {
            uint2v o;
            o[0] = cvtpk(Ov[nd][qt][0] * inv, Ov[nd][qt][1] * inv);
            o[1] = cvtpk(Ov[nd][qt][2] * inv, Ov[nd][qt][3] * inv);
            *(uint2v*)(&attnb[rowb + nd * 16]) = o;
        }
    }
}

// ---------------------------------------------------------------------------
extern "C" void kernel_launch(void* const* d_in, const int* in_sizes, int n_in,
                              void* d_out, int out_size, void* d_ws, size_t ws_size,
                              hipStream_t stream) {
    (void)in_sizes; (void)n_in; (void)out_size; (void)ws_size;
    const float* hid  = (const float*)d_in[0];
    const float* mask = (const float*)d_in[1];
    const float* Wq = (const float*)d_in[2];
    const float* bq = (const float*)d_in[3];
    const float* Wk = (const float*)d_in[4];
    const float* bk = (const float*)d_in[5];
    const float* Wv = (const float*)d_in[6];
    const float* bv = (const float*)d_in[7];
    const float* Wo = (const float*)d_in[8];
    const float* bo = (const float*)d_in[9];
    float* out = (float*)d_out;

    char* ws = (char*)d_ws;
    u16* hidb  = (u16*)(ws);
    u16* wt    = (u16*)(ws + (16u << 20));
    u16* Qh    = (u16*)(ws + (24u << 20));
    u16* Kh    = (u16*)(ws + (40u << 20));
    u16* Vtb   = (u16*)(ws + (56u << 20));   // V^T [B][H][64][4096]
    u16* attnb = (u16*)(ws + (72u << 20));

    cvt_k<<<dim3(8192), dim3(256), 0, stream>>>(hid, hidb, 8388608);
    transw_k<<<dim3(16, 16, 4), dim3(256), 0, stream>>>(Wq, Wk, Wv, Wo, wt);
    gemm_t<0><<<dim3(64, 16), dim3(256), 0, stream>>>(hidb, wt, bq, bk,
                                                      Qh, Kh, (float*)nullptr);
    gemm_t<2><<<dim3(64, 8), dim3(256), 0, stream>>>(hidb, wt + 2 * 1048576, bv, (const float*)nullptr,
                                                     Vtb, (u16*)nullptr, (float*)nullptr);
    attn_k<<<dim3(1024), dim3(256), 0, stream>>>(Qh, Kh, Vtb, mask, attnb);
    gemm_t<1><<<dim3(64, 8), dim3(256), 0, stream>>>(attnb, wt + 3 * 1048576, bo, (const float*)nullptr,
                                                     (u16*)nullptr, (u16*)nullptr, out);
}